// Round 4
// baseline (430.619 us; speedup 1.0000x reference)
//
#include <hip/hip_runtime.h>
#include <hip/hip_bf16.h>
#include <stdint.h>

typedef unsigned short u16;
typedef __bf16 bf16_t;
typedef bf16_t bf16x8 __attribute__((ext_vector_type(8)));
typedef float f32x4 __attribute__((ext_vector_type(4)));
typedef short short8 __attribute__((ext_vector_type(8)));
typedef short short4v __attribute__((ext_vector_type(4)));
typedef u16 u16x4 __attribute__((ext_vector_type(4)));

#define C_EMBD 768
#define NHEAD 12
#define HD 64
#define SEQ 4096
#define BATCH 2
#define M_TOK (BATCH * SEQ)   // 8192
#define N_QKV (3 * C_EMBD)    // 2304

__device__ __forceinline__ u16 f2bf(float f) {
  return __builtin_bit_cast(u16, (bf16_t)f);
}
__device__ __forceinline__ bf16x8 ld8(const u16* p) {
  return __builtin_bit_cast(bf16x8, *reinterpret_cast<const short8*>(p));
}
__device__ __forceinline__ void async16(const u16* g, u16* l) {
  __builtin_amdgcn_global_load_lds(
      (__attribute__((address_space(1))) void*)g,
      (__attribute__((address_space(3))) void*)l, 16, 0, 0);
}

#define MFMA32(a, b, c) __builtin_amdgcn_mfma_f32_16x16x32_bf16(a, b, c, 0, 0, 0)

__device__ __forceinline__ f32x4 mfma16(short4v a, short4v b, f32x4 c) {
#if __has_builtin(__builtin_amdgcn_mfma_f32_16x16x16bf16_1k)
  return __builtin_amdgcn_mfma_f32_16x16x16bf16_1k(a, b, c, 0, 0, 0);
#else
  asm volatile("v_mfma_f32_16x16x16_bf16 %0, %1, %2, %0"
               : "+v"(c) : "v"(a), "v"(b));
  return c;
#endif
}

// ---------------- fp32 -> bf16 convert (x) ----------------
__global__ __launch_bounds__(256) void k_convert(const float* __restrict__ in,
                                                 u16* __restrict__ out, int n4) {
  int i = blockIdx.x * blockDim.x + threadIdx.x;
  int stride = gridDim.x * blockDim.x;
  for (; i < n4; i += stride) {
    float4 v = reinterpret_cast<const float4*>(in)[i];
    u16x4 o;
    o.x = f2bf(v.x); o.y = f2bf(v.y); o.z = f2bf(v.z); o.w = f2bf(v.w);
    reinterpret_cast<u16x4*>(out)[i] = o;
  }
}

// ------------- transpose + convert weights: W[R][C] -> WT[C][R] bf16 -------------
__global__ __launch_bounds__(256) void k_tconv(const float* __restrict__ W,
                                               u16* __restrict__ WT, int R, int C) {
  __shared__ float t[32][33];
  int c0 = blockIdx.x * 32, r0 = blockIdx.y * 32;
  int tid = threadIdx.x;
  int a = tid >> 3, b = (tid & 7) * 4;
  float4 v = *reinterpret_cast<const float4*>(W + (size_t)(r0 + a) * C + c0 + b);
  t[a][b] = v.x; t[a][b + 1] = v.y; t[a][b + 2] = v.z; t[a][b + 3] = v.w;
  __syncthreads();
  u16x4 o;
  o.x = f2bf(t[b + 0][a]); o.y = f2bf(t[b + 1][a]);
  o.z = f2bf(t[b + 2][a]); o.w = f2bf(t[b + 3][a]);
  *reinterpret_cast<u16x4*>(WT + (size_t)(c0 + a) * R + r0 + b) = o;
}

// ------------- GEMM: C[M,N] = A[M,K] * Bt[N,K]^T + bias -------------
template <int MODE>
__global__ __launch_bounds__(256) void k_gemm(const u16* __restrict__ A,
                                              const u16* __restrict__ Bt,
                                              const float* __restrict__ bias,
                                              u16* __restrict__ q_out,
                                              u16* __restrict__ k_out,
                                              u16* __restrict__ v_out,
                                              float* __restrict__ fout, int K) {
  __shared__ __align__(16) u16 lA[128 * 32];
  __shared__ __align__(16) u16 lB[128 * 32];
  int tid = threadIdx.x;
  int bm = blockIdx.x, bn = blockIdx.y;
  int w = tid >> 6, l = tid & 63;
  int wr = w >> 1, wc = w & 1;
  int lrow = l & 15, lk = (l >> 4) * 8;
  f32x4 acc[4][4] = {};

  int srow = tid >> 2, scol = (tid & 3) * 8;
  const u16* gA0 = A + (size_t)(bm * 128 + srow) * K + scol;
  const u16* gA1 = A + (size_t)(bm * 128 + 64 + srow) * K + scol;
  const u16* gB0 = Bt + (size_t)(bn * 128 + srow) * K + scol;
  const u16* gB1 = Bt + (size_t)(bn * 128 + 64 + srow) * K + scol;
  u16* lA0 = lA + w * 512;
  u16* lA1 = lA + 2048 + w * 512;
  u16* lB0 = lB + w * 512;
  u16* lB1 = lB + 2048 + w * 512;

  for (int k0 = 0; k0 < K; k0 += 32) {
    __syncthreads();
    async16(gA0 + k0, lA0);
    async16(gA1 + k0, lA1);
    async16(gB0 + k0, lB0);
    async16(gB1 + k0, lB1);
    __syncthreads();
    bf16x8 af[4], bfr[4];
#pragma unroll
    for (int mf = 0; mf < 4; ++mf)
      af[mf] = ld8(&lA[(wr * 64 + mf * 16 + lrow) * 32 + lk]);
#pragma unroll
    for (int nf = 0; nf < 4; ++nf)
      bfr[nf] = ld8(&lB[(wc * 64 + nf * 16 + lrow) * 32 + lk]);
#pragma unroll
    for (int mf = 0; mf < 4; ++mf)
#pragma unroll
      for (int nf = 0; nf < 4; ++nf)
        acc[mf][nf] = __builtin_amdgcn_mfma_f32_16x16x32_bf16(
            af[mf], bfr[nf], acc[mf][nf], 0, 0, 0);
  }

#pragma unroll
  for (int nf = 0; nf < 4; ++nf) {
    int col = bn * 128 + wc * 64 + nf * 16 + lrow;
    float bv = bias[col];
#pragma unroll
    for (int mf = 0; mf < 4; ++mf) {
      int row0 = bm * 128 + wr * 64 + mf * 16 + (l >> 4) * 4;
#pragma unroll
      for (int r = 0; r < 4; ++r) {
        float val = acc[mf][nf][r] + bv;
        int row = row0 + r;
        if constexpr (MODE == 0) {
          int which = (col >= 2 * C_EMBD) ? 2 : ((col >= C_EMBD) ? 1 : 0);
          int wi = col - which * C_EMBD;
          int head = wi >> 6, dd = wi & 63;
          int b = row >> 12, n = row & 4095;
          if (which == 2) {
            v_out[(((size_t)b * NHEAD + head) * HD + dd) * SEQ + n] = f2bf(val);
          } else {
            u16* dst = (which == 0) ? q_out : k_out;
            dst[(((size_t)b * NHEAD + head) * SEQ + n) * HD + dd] = f2bf(val);
          }
        } else {
          fout[(size_t)row * C_EMBD + col] = val;
        }
      }
    }
  }
}

// ------------- attention helpers -------------
__device__ __forceinline__ void process(f32x4 (&s4)[4], float& mst, float& lsum,
                                        f32x4 (&o)[4], short4v (&pb)[4],
                                        bool diag, int qrow, int t, int g) {
  const float CE = 0.125f * 1.44269504088896f;  // scale * log2(e)
  if (diag) {
    int kb = 64 * t + 4 * g;
#pragma unroll
    for (int kvf = 0; kvf < 4; ++kvf)
#pragma unroll
      for (int r = 0; r < 4; ++r)
        if (kb + 16 * kvf + r > qrow) s4[kvf][r] = -1e30f;
  }
  f32x4 mx = s4[0];
#pragma unroll
  for (int kvf = 1; kvf < 4; ++kvf)
#pragma unroll
    for (int r = 0; r < 4; ++r) mx[r] = fmaxf(mx[r], s4[kvf][r]);
  float rmax = fmaxf(fmaxf(mx[0], mx[1]), fmaxf(mx[2], mx[3]));
  rmax = fmaxf(rmax, __shfl_xor(rmax, 16));
  rmax = fmaxf(rmax, __shfl_xor(rmax, 32));
  bool keep = __all(rmax <= mst + 44.0f);  // defer-max: P bounded by 2^8
  float mnew = keep ? mst : fmaxf(mst, rmax);
  float mCE = mnew * CE;
  float rs = 0.f;
#pragma unroll
  for (int kvf = 0; kvf < 4; ++kvf) {
    f32x4 pf;
#pragma unroll
    for (int r = 0; r < 4; ++r) {
      pf[r] = exp2f(s4[kvf][r] * CE - mCE);
      pb[kvf][r] = (short)f2bf(pf[r]);
    }
    rs += (pf[0] + pf[1]) + (pf[2] + pf[3]);
  }
  rs += __shfl_xor(rs, 16);
  rs += __shfl_xor(rs, 32);
  if (keep) {
    lsum += rs;
  } else {
    float sc = exp2f((mst - mnew) * CE);
    lsum = lsum * sc + rs;
#pragma unroll
    for (int df = 0; df < 4; ++df) o[df] *= sc;
    mst = mnew;
  }
}

__device__ __forceinline__ void store16(u16* __restrict__ O, const f32x4 (&o)[4],
                                        float ssum, int b, int h, int q, int g) {
  float inv = 1.0f / ssum;
  size_t base = ((size_t)b * SEQ + q) * C_EMBD + h * HD;
#pragma unroll
  for (int df = 0; df < 4; ++df) {
    u16x4 pk;
#pragma unroll
    for (int r = 0; r < 4; ++r) pk[r] = f2bf(o[df][r] * inv);
    *reinterpret_cast<u16x4*>(&O[base + df * 16 + 4 * g]) = pk;
  }
}

// ------------- causal flash attention, software-pipelined -------------
// 768 blocks, 4 waves. Wave w of block (B-permuted) owns granule pair
// {u = 4B+w, 255-u}. Pipeline: QK(t+1) || softmax(t) -> PV(t).
// K double-buffered, V triple-buffered, 1 barrier/iter.
// V LDS: chunk-swizzle (c^(r&7)) + half-swap on r&8 -> conflict-free b64 reads.
__global__ __launch_bounds__(256, 3) void k_attn(const u16* __restrict__ Q,
                                                 const u16* __restrict__ Kb,
                                                 const u16* __restrict__ VTb,
                                                 u16* __restrict__ O) {
  int blk = blockIdx.x;
  int xcd = blk & 7, ix = blk >> 3;
  int bh = xcd * 3 + (ix >> 5);  // 3 bh per XCD for K/V L2 locality
  int B = ((ix & 31) * 17 + 5 * (ix >> 5)) & 31;  // scatter B for CU balance
  const u16* Qh = Q + (size_t)bh * SEQ * HD;
  const u16* Kh = Kb + (size_t)bh * SEQ * HD;
  const u16* Vh = VTb + (size_t)bh * HD * SEQ;  // [64][4096]
  int tid = threadIdx.x, w = tid >> 6, l = tid & 63;
  int i = l & 15, g = l >> 4;

  __shared__ __align__(16) u16 lK[2][64 * 64];
  __shared__ __align__(16) u16 lV[3][64 * 64];

  int u_lo = 4 * B + w, u_hi = 255 - u_lo;
  int q_lo = 16 * u_lo + i, q_hi = 16 * u_hi + i;
  bf16x8 qlo0 = ld8(Qh + (size_t)q_lo * HD + g * 8);
  bf16x8 qlo1 = ld8(Qh + (size_t)q_lo * HD + 32 + g * 8);
  bf16x8 qhi0 = ld8(Qh + (size_t)q_hi * HD + g * 8);
  bf16x8 qhi1 = ld8(Qh + (size_t)q_hi * HD + 32 + g * 8);
  f32x4 o_lo[4] = {}, o_hi[4] = {};
  float m_lo = -1e30f, s_lo = 0.f, m_hi = -1e30f, s_hi = 0.f;

  // staging addresses: thread covers rows r0, r0+32; 16B K chunks, 2x8B V halves
  int r0 = tid >> 3, c0 = tid & 7;
  int cs = c0 ^ (r0 & 7);
  int sw = (r0 >> 3) & 1;  // half-swap bit (same for r0 and r0+32)
  const u16* gK0 = Kh + r0 * HD + 8 * cs;
  const u16* gK1 = gK0 + 32 * HD;
  const u16* gVa = Vh + (size_t)r0 * SEQ + 8 * cs + 4 * sw;
  const u16* gVb = Vh + (size_t)r0 * SEQ + 8 * cs + 4 * (sw ^ 1);
  const u16* gVc = gVa + 32 * SEQ;
  const u16* gVd = gVb + 32 * SEQ;
  int dst0 = 64 * r0 + 8 * c0, dst1 = dst0 + 2048;

  // fragment addresses (u16 indices into 64x64 swizzled tiles)
  int koff0 = 64 * i + 8 * (g ^ (i & 7));
  int koff1 = 64 * i + 8 * ((g + 4) ^ (i & 7));
  int kvx = (i >> 1) & 3;
  int vbit = (g >> 1) ^ (i & 1);
  int vhalf = 4 * ((g & 1) ^ (i >> 3));
  int voff[4];
#pragma unroll
  for (int kvf = 0; kvf < 4; ++kvf)
    voff[kvf] = 64 * i + 8 * ((2 * (kvf ^ kvx)) | vbit) + vhalf;

  const int NT = 64 - B;

  auto qk = [&](int t1, f32x4 (&shn)[4], f32x4 (&sln)[4], bool doLoN) {
    const u16* lKn = lK[t1 & 1];
    __builtin_amdgcn_s_setprio(1);
#pragma unroll
    for (int kvf = 0; kvf < 4; ++kvf) {
      bf16x8 kf0 = ld8(&lKn[koff0 + 1024 * kvf]);
      bf16x8 kf1 = ld8(&lKn[koff1 + 1024 * kvf]);
      shn[kvf] = MFMA32(kf0, qhi0, shn[kvf]);
      shn[kvf] = MFMA32(kf1, qhi1, shn[kvf]);
      if (doLoN) {
        sln[kvf] = MFMA32(kf0, qlo0, sln[kvf]);
        sln[kvf] = MFMA32(kf1, qlo1, sln[kvf]);
      }
    }
    __builtin_amdgcn_s_setprio(0);
  };

  auto stage = [&](int t) {  // prologue: load + write tile t
    short8 k0 = *(const short8*)(gK0 + t * 64 * HD);
    short8 k1 = *(const short8*)(gK1 + t * 64 * HD);
    short4v a0 = *(const short4v*)(gVa + t * 64);
    short4v a1 = *(const short4v*)(gVb + t * 64);
    short4v b0 = *(const short4v*)(gVc + t * 64);
    short4v b1 = *(const short4v*)(gVd + t * 64);
    u16* nK = lK[t & 1];
    u16* nV = lV[t % 3];
    *(short8*)&nK[dst0] = k0; *(short8*)&nK[dst1] = k1;
    *(short4v*)&nV[dst0] = a0; *(short4v*)&nV[dst0 + 4] = a1;
    *(short4v*)&nV[dst1] = b0; *(short4v*)&nV[dst1 + 4] = b1;
  };

  auto iter = [&](int t, f32x4 (&sh)[4], f32x4 (&sl)[4],
                  f32x4 (&shn)[4], f32x4 (&sln)[4]) {
    bool hasNext = (t + 1) < NT;
    bool hasStage = (t + 2) < NT;
    short8 ka, kb;
    short4v va0, va1, vb0, vb1;
    if (hasStage) {  // issue global loads for tile t+2 (consumed post-PV)
      int o2 = t + 2;
      ka = *(const short8*)(gK0 + o2 * 64 * HD);
      kb = *(const short8*)(gK1 + o2 * 64 * HD);
      va0 = *(const short4v*)(gVa + o2 * 64);
      va1 = *(const short4v*)(gVb + o2 * 64);
      vb0 = *(const short4v*)(gVc + o2 * 64);
      vb1 = *(const short4v*)(gVd + o2 * 64);
    }
    bool doLoN = (t + 1) <= B;
    if (hasNext) {  // QK(t+1) on MFMA pipe, overlaps softmax(t) VALU below
#pragma unroll
      for (int kvf = 0; kvf < 4; ++kvf) {
        shn[kvf] = f32x4{};
        if (doLoN) sln[kvf] = f32x4{};
      }
      qk(t + 1, shn, sln, doLoN);
    }
    short4v pbh[4], pbl[4];
    bool doLo = t <= B;
    process(sh, m_hi, s_hi, o_hi, pbh, t == NT - 1, q_hi, t, g);
    if (doLo) process(sl, m_lo, s_lo, o_lo, pbl, t == B, q_lo, t, g);
    {  // PV(t)
      const u16* lVb = lV[t % 3];
      __builtin_amdgcn_s_setprio(1);
#pragma unroll
      for (int df = 0; df < 4; ++df)
#pragma unroll
        for (int kvf = 0; kvf < 4; ++kvf) {
          short4v vf = *reinterpret_cast<const short4v*>(&lVb[voff[kvf] + 1024 * df]);
          o_hi[df] = mfma16(vf, pbh[kvf], o_hi[df]);
          if (doLo) o_lo[df] = mfma16(vf, pbl[kvf], o_lo[df]);
        }
      __builtin_amdgcn_s_setprio(0);
    }
    if (hasStage) {
      u16* nK = lK[t & 1];          // == (t+2)&1
      u16* nV = lV[(t + 2) % 3];
      *(short8*)&nK[dst0] = ka; *(short8*)&nK[dst1] = kb;
      *(short4v*)&nV[dst0] = va0; *(short4v*)&nV[dst0 + 4] = va1;
      *(short4v*)&nV[dst1] = vb0; *(short4v*)&nV[dst1 + 4] = vb1;
    }
    if (hasNext) __syncthreads();
  };

  stage(0);
  stage(1);
  __syncthreads();

  f32x4 shA[4], slA[4], shB[4], slB[4];
#pragma unroll
  for (int kvf = 0; kvf < 4; ++kvf) { shA[kvf] = f32x4{}; slA[kvf] = f32x4{}; }
  qk(0, shA, slA, true);

  for (int t = 0; t < NT; t += 2) {
    iter(t, shA, slA, shB, slB);
    if (t + 1 < NT) iter(t + 1, shB, slB, shA, slA);
  }

  int b = bh / NHEAD, h = bh % NHEAD;
  store16(O, o_hi, s_hi, b, h, q_hi, g);
  store16(O, o_lo, s_lo, b, h, q_lo, g);
}

extern "C" void kernel_launch(void* const* d_in, const int* in_sizes, int n_in,
                              void* d_out, int out_size, void* d_ws, size_t ws_size,
                              hipStream_t stream) {
  const float* x = (const float*)d_in[0];
  const float* W_attn = (const float*)d_in[1];
  const float* b_attn = (const float*)d_in[2];
  const float* W_out = (const float*)d_in[3];
  const float* b_out = (const float*)d_in[4];
  float* out = (float*)d_out;

  char* ws = (char*)d_ws;
  u16* xb = (u16*)(ws + 0);              // 8192*768*2       = 12,582,912
  u16* waT = (u16*)(ws + 12582912);      // 2304*768*2       =  3,538,944
  u16* woT = (u16*)(ws + 16121856);      // 768*768*2        =  1,179,648
  u16* q = (u16*)(ws + 17301504);        // 12,582,912
  u16* kk = (u16*)(ws + 29884416);       // 12,582,912
  u16* v = (u16*)(ws + 42467328);        // 12,582,912  (transposed [b][h][d][n])
  u16* ao = (u16*)(ws + 67633152);       // 12,582,912  (end 80,216,064)

  k_convert<<<1536, 256, 0, stream>>>(x, xb, M_TOK * C_EMBD / 4);
  k_tconv<<<dim3(N_QKV / 32, C_EMBD / 32), 256, 0, stream>>>(W_attn, waT, C_EMBD, N_QKV);
  k_tconv<<<dim3(C_EMBD / 32, C_EMBD / 32), 256, 0, stream>>>(W_out, woT, C_EMBD, C_EMBD);
  k_gemm<0><<<dim3(M_TOK / 128, N_QKV / 128), 256, 0, stream>>>(
      xb, waT, b_attn, q, kk, v, nullptr, C_EMBD);
  k_attn<<<768, 256, 0, stream>>>(q, kk, v, ao);
  k_gemm<1><<<dim3(M_TOK / 128, C_EMBD / 128), 256, 0, stream>>>(
      ao, woT, b_out, nullptr, nullptr, nullptr, out, C_EMBD);
}

// Round 5
// 338.430 us; speedup vs baseline: 1.2724x; 1.2724x over previous
//
#include <hip/hip_runtime.h>
#include <hip/hip_bf16.h>
#include <stdint.h>

typedef unsigned short u16;
typedef __bf16 bf16_t;
typedef bf16_t bf16x8 __attribute__((ext_vector_type(8)));
typedef float f32x4 __attribute__((ext_vector_type(4)));
typedef short short8 __attribute__((ext_vector_type(8)));
typedef short short4v __attribute__((ext_vector_type(4)));
typedef u16 u16x4 __attribute__((ext_vector_type(4)));

#define C_EMBD 768
#define NHEAD 12
#define HD 64
#define SEQ 4096
#define BATCH 2
#define M_TOK (BATCH * SEQ)   // 8192
#define N_QKV (3 * C_EMBD)    // 2304

__device__ __forceinline__ u16 f2bf(float f) {
  return __builtin_bit_cast(u16, (bf16_t)f);
}
__device__ __forceinline__ bf16x8 ld8(const u16* p) {
  return __builtin_bit_cast(bf16x8, *reinterpret_cast<const short8*>(p));
}
__device__ __forceinline__ void async16(const u16* g, u16* l) {
  __builtin_amdgcn_global_load_lds(
      (__attribute__((address_space(1))) void*)g,
      (__attribute__((address_space(3))) void*)l, 16, 0, 0);
}

#define MFMA32(a, b, c) __builtin_amdgcn_mfma_f32_16x16x32_bf16(a, b, c, 0, 0, 0)

__device__ __forceinline__ f32x4 mfma16(short4v a, short4v b, f32x4 c) {
#if __has_builtin(__builtin_amdgcn_mfma_f32_16x16x16bf16_1k)
  return __builtin_amdgcn_mfma_f32_16x16x16bf16_1k(a, b, c, 0, 0, 0);
#else
  asm volatile("v_mfma_f32_16x16x16_bf16 %0, %1, %2, %0"
               : "+v"(c) : "v"(a), "v"(b));
  return c;
#endif
}

// ---------------- fp32 -> bf16 convert (x) ----------------
__global__ __launch_bounds__(256) void k_convert(const float* __restrict__ in,
                                                 u16* __restrict__ out, int n4) {
  int i = blockIdx.x * blockDim.x + threadIdx.x;
  int stride = gridDim.x * blockDim.x;
  for (; i < n4; i += stride) {
    float4 v = reinterpret_cast<const float4*>(in)[i];
    u16x4 o;
    o.x = f2bf(v.x); o.y = f2bf(v.y); o.z = f2bf(v.z); o.w = f2bf(v.w);
    reinterpret_cast<u16x4*>(out)[i] = o;
  }
}

// ------------- transpose + convert weights: W[R][C] -> WT[C][R] bf16 -------------
__global__ __launch_bounds__(256) void k_tconv(const float* __restrict__ W,
                                               u16* __restrict__ WT, int R, int C) {
  __shared__ float t[32][33];
  int c0 = blockIdx.x * 32, r0 = blockIdx.y * 32;
  int tid = threadIdx.x;
  int a = tid >> 3, b = (tid & 7) * 4;
  float4 v = *reinterpret_cast<const float4*>(W + (size_t)(r0 + a) * C + c0 + b);
  t[a][b] = v.x; t[a][b + 1] = v.y; t[a][b + 2] = v.z; t[a][b + 3] = v.w;
  __syncthreads();
  u16x4 o;
  o.x = f2bf(t[b + 0][a]); o.y = f2bf(t[b + 1][a]);
  o.z = f2bf(t[b + 2][a]); o.w = f2bf(t[b + 3][a]);
  *reinterpret_cast<u16x4*>(WT + (size_t)(c0 + a) * R + r0 + b) = o;
}

// ------------- GEMM: C[M,N] = A[M,K] * Bt[N,K]^T + bias -------------
template <int MODE>
__global__ __launch_bounds__(256) void k_gemm(const u16* __restrict__ A,
                                              const u16* __restrict__ Bt,
                                              const float* __restrict__ bias,
                                              u16* __restrict__ q_out,
                                              u16* __restrict__ k_out,
                                              u16* __restrict__ v_out,
                                              float* __restrict__ fout, int K) {
  __shared__ __align__(16) u16 lA[128 * 32];
  __shared__ __align__(16) u16 lB[128 * 32];
  int tid = threadIdx.x;
  int bm = blockIdx.x, bn = blockIdx.y;
  int w = tid >> 6, l = tid & 63;
  int wr = w >> 1, wc = w & 1;
  int lrow = l & 15, lk = (l >> 4) * 8;
  f32x4 acc[4][4] = {};

  int srow = tid >> 2, scol = (tid & 3) * 8;
  const u16* gA0 = A + (size_t)(bm * 128 + srow) * K + scol;
  const u16* gA1 = A + (size_t)(bm * 128 + 64 + srow) * K + scol;
  const u16* gB0 = Bt + (size_t)(bn * 128 + srow) * K + scol;
  const u16* gB1 = Bt + (size_t)(bn * 128 + 64 + srow) * K + scol;
  u16* lA0 = lA + w * 512;
  u16* lA1 = lA + 2048 + w * 512;
  u16* lB0 = lB + w * 512;
  u16* lB1 = lB + 2048 + w * 512;

  for (int k0 = 0; k0 < K; k0 += 32) {
    __syncthreads();
    async16(gA0 + k0, lA0);
    async16(gA1 + k0, lA1);
    async16(gB0 + k0, lB0);
    async16(gB1 + k0, lB1);
    __syncthreads();
    bf16x8 af[4], bfr[4];
#pragma unroll
    for (int mf = 0; mf < 4; ++mf)
      af[mf] = ld8(&lA[(wr * 64 + mf * 16 + lrow) * 32 + lk]);
#pragma unroll
    for (int nf = 0; nf < 4; ++nf)
      bfr[nf] = ld8(&lB[(wc * 64 + nf * 16 + lrow) * 32 + lk]);
#pragma unroll
    for (int mf = 0; mf < 4; ++mf)
#pragma unroll
      for (int nf = 0; nf < 4; ++nf)
        acc[mf][nf] = __builtin_amdgcn_mfma_f32_16x16x32_bf16(
            af[mf], bfr[nf], acc[mf][nf], 0, 0, 0);
  }

#pragma unroll
  for (int nf = 0; nf < 4; ++nf) {
    int col = bn * 128 + wc * 64 + nf * 16 + lrow;
    float bv = bias[col];
#pragma unroll
    for (int mf = 0; mf < 4; ++mf) {
      int row0 = bm * 128 + wr * 64 + mf * 16 + (l >> 4) * 4;
#pragma unroll
      for (int r = 0; r < 4; ++r) {
        float val = acc[mf][nf][r] + bv;
        int row = row0 + r;
        if constexpr (MODE == 0) {
          int which = (col >= 2 * C_EMBD) ? 2 : ((col >= C_EMBD) ? 1 : 0);
          int wi = col - which * C_EMBD;
          int head = wi >> 6, dd = wi & 63;
          int b = row >> 12, n = row & 4095;
          if (which == 2) {
            v_out[(((size_t)b * NHEAD + head) * HD + dd) * SEQ + n] = f2bf(val);
          } else {
            u16* dst = (which == 0) ? q_out : k_out;
            dst[(((size_t)b * NHEAD + head) * SEQ + n) * HD + dd] = f2bf(val);
          }
        } else {
          fout[(size_t)row * C_EMBD + col] = val;
        }
      }
    }
  }
}

// ------------- attention helpers -------------
#define CE_CONST (0.125f * 1.44269504088896f)  // scale * log2(e)

__device__ __forceinline__ void mask_diag(f32x4 (&s4)[4], int qrow, int t, int g) {
  int kb = 64 * t + 4 * g;
#pragma unroll
  for (int kvf = 0; kvf < 4; ++kvf)
#pragma unroll
    for (int r = 0; r < 4; ++r)
      if (kb + 16 * kvf + r > qrow) s4[kvf][r] = -1e30f;
}

// single-stream softmax (tail iterations, hi only)
__device__ __forceinline__ void process1(f32x4 (&s4)[4], float& mst, float& lsum,
                                         f32x4 (&o)[4], short4v (&pb)[4],
                                         bool diag, int qrow, int t, int g) {
  if (diag) mask_diag(s4, qrow, t, g);
  f32x4 mx = s4[0];
#pragma unroll
  for (int kvf = 1; kvf < 4; ++kvf)
#pragma unroll
    for (int r = 0; r < 4; ++r) mx[r] = fmaxf(mx[r], s4[kvf][r]);
  float rmax = fmaxf(fmaxf(mx[0], mx[1]), fmaxf(mx[2], mx[3]));
  rmax = fmaxf(rmax, __shfl_xor(rmax, 16));
  rmax = fmaxf(rmax, __shfl_xor(rmax, 32));
  bool keep = __all(rmax <= mst + 44.0f);  // defer-max: P bounded by 2^8
  float mnew = keep ? mst : fmaxf(mst, rmax);
  float mCE = mnew * CE_CONST;
  float rs = 0.f;
#pragma unroll
  for (int kvf = 0; kvf < 4; ++kvf) {
    f32x4 pf;
#pragma unroll
    for (int r = 0; r < 4; ++r) {
      pf[r] = exp2f(s4[kvf][r] * CE_CONST - mCE);
      pb[kvf][r] = (short)f2bf(pf[r]);
    }
    rs += (pf[0] + pf[1]) + (pf[2] + pf[3]);
  }
  rs += __shfl_xor(rs, 16);
  rs += __shfl_xor(rs, 32);
  if (keep) {
    lsum += rs;
  } else {
    float sc = exp2f((mst - mnew) * CE_CONST);
    lsum = lsum * sc + rs;
#pragma unroll
    for (int df = 0; df < 4; ++df) o[df] *= sc;
    mst = mnew;
  }
}

// dual-stream softmax: straight-line so the two independent chains (shfl
// latency ~120cy each, exp/cvt pipelines) interleave on the VALU/LDS pipes.
__device__ __forceinline__ void process2(
    f32x4 (&sh)[4], float& mh, float& lh, f32x4 (&oh)[4], short4v (&ph)[4],
    bool diagH, int qH,
    f32x4 (&sl)[4], float& ml, float& ll, f32x4 (&ol)[4], short4v (&pl)[4],
    bool diagL, int qL, int t, int g) {
  if (diagH) mask_diag(sh, qH, t, g);
  if (diagL) mask_diag(sl, qL, t, g);
  f32x4 mxh = sh[0], mxl = sl[0];
#pragma unroll
  for (int kvf = 1; kvf < 4; ++kvf)
#pragma unroll
    for (int r = 0; r < 4; ++r) {
      mxh[r] = fmaxf(mxh[r], sh[kvf][r]);
      mxl[r] = fmaxf(mxl[r], sl[kvf][r]);
    }
  float rmh = fmaxf(fmaxf(mxh[0], mxh[1]), fmaxf(mxh[2], mxh[3]));
  float rml = fmaxf(fmaxf(mxl[0], mxl[1]), fmaxf(mxl[2], mxl[3]));
  float th = __shfl_xor(rmh, 16);
  float tl = __shfl_xor(rml, 16);
  rmh = fmaxf(rmh, th); rml = fmaxf(rml, tl);
  th = __shfl_xor(rmh, 32);
  tl = __shfl_xor(rml, 32);
  rmh = fmaxf(rmh, th); rml = fmaxf(rml, tl);
  bool keep = __all(fmaxf(rmh - mh, rml - ml) <= 44.0f);
  float mnh = keep ? mh : fmaxf(mh, rmh);
  float mnl = keep ? ml : fmaxf(ml, rml);
  float ceh = mnh * CE_CONST, cel = mnl * CE_CONST;
  float rsh = 0.f, rsl = 0.f;
#pragma unroll
  for (int kvf = 0; kvf < 4; ++kvf) {
    f32x4 pfh, pfl;
#pragma unroll
    for (int r = 0; r < 4; ++r) {
      pfh[r] = exp2f(sh[kvf][r] * CE_CONST - ceh);
      pfl[r] = exp2f(sl[kvf][r] * CE_CONST - cel);
      ph[kvf][r] = (short)f2bf(pfh[r]);
      pl[kvf][r] = (short)f2bf(pfl[r]);
    }
    rsh += (pfh[0] + pfh[1]) + (pfh[2] + pfh[3]);
    rsl += (pfl[0] + pfl[1]) + (pfl[2] + pfl[3]);
  }
  th = __shfl_xor(rsh, 16);
  tl = __shfl_xor(rsl, 16);
  rsh += th; rsl += tl;
  th = __shfl_xor(rsh, 32);
  tl = __shfl_xor(rsl, 32);
  rsh += th; rsl += tl;
  if (keep) {
    lh += rsh; ll += rsl;
  } else {
    float sch = exp2f((mh - mnh) * CE_CONST);
    float scl = exp2f((ml - mnl) * CE_CONST);
    lh = lh * sch + rsh; ll = ll * scl + rsl;
#pragma unroll
    for (int df = 0; df < 4; ++df) { oh[df] *= sch; ol[df] *= scl; }
    mh = mnh; ml = mnl;
  }
}

__device__ __forceinline__ void store16(u16* __restrict__ O, const f32x4 (&o)[4],
                                        float ssum, int b, int h, int q, int g) {
  float inv = 1.0f / ssum;
  size_t base = ((size_t)b * SEQ + q) * C_EMBD + h * HD;
#pragma unroll
  for (int df = 0; df < 4; ++df) {
    u16x4 pk;
#pragma unroll
    for (int r = 0; r < 4; ++r) pk[r] = f2bf(o[df][r] * inv);
    *reinterpret_cast<u16x4*>(&O[base + df * 16 + 4 * g]) = pk;
  }
}

// ------------- causal flash attention -------------
// 768 blocks, 4 waves. Wave w of block (B scattered) owns 16-row granule pair
// {u = 4B+w, 255-u}. NT = 64-B identical for all waves; lo active for t<=B;
// per-wave work = 65 tile-units for EVERY wave (perfect balance).
// Dual-stream iterations run one straight-line interleaved softmax (ILP).
__global__ __launch_bounds__(256, 3) void k_attn(const u16* __restrict__ Q,
                                                 const u16* __restrict__ Kb,
                                                 const u16* __restrict__ VTb,
                                                 u16* __restrict__ O) {
  int blk = blockIdx.x;
  int xcd = blk & 7, ix = blk >> 3;
  int bh = xcd * 3 + (ix >> 5);  // 3 bh per XCD for K/V L2 locality
  int B = ((ix & 31) * 17 + 5 * (ix >> 5)) & 31;  // scatter B for CU balance
  const u16* Qh = Q + (size_t)bh * SEQ * HD;
  const u16* Kh = Kb + (size_t)bh * SEQ * HD;
  const u16* Vh = VTb + (size_t)bh * HD * SEQ;  // [64][4096]
  int tid = threadIdx.x, w = tid >> 6, l = tid & 63;
  int i = l & 15, g = l >> 4;

  __shared__ __align__(16) u16 lK[2][64 * 64];
  __shared__ __align__(16) u16 lV[2][64 * 64];

  int u_lo = 4 * B + w, u_hi = 255 - u_lo;
  int q_lo = 16 * u_lo + i, q_hi = 16 * u_hi + i;
  bf16x8 qlo0 = ld8(Qh + (size_t)q_lo * HD + g * 8);
  bf16x8 qlo1 = ld8(Qh + (size_t)q_lo * HD + 32 + g * 8);
  bf16x8 qhi0 = ld8(Qh + (size_t)q_hi * HD + g * 8);
  bf16x8 qhi1 = ld8(Qh + (size_t)q_hi * HD + 32 + g * 8);
  f32x4 o_lo[4] = {}, o_hi[4] = {};
  float m_lo = -1e30f, s_lo = 0.f, m_hi = -1e30f, s_hi = 0.f;

  // staging: 256 threads x (2 K-chunks + 2 V-chunks) of 16B
  int r0 = tid >> 3, c0 = tid & 7;
  int cs0 = c0 ^ (r0 & 7);
  int r1 = r0 + 32, cs1 = c0 ^ (r1 & 7);
  const u16* gK0 = Kh + r0 * HD + 8 * cs0;
  const u16* gK1 = Kh + r1 * HD + 8 * cs1;
  const u16* gV0 = Vh + (size_t)r0 * SEQ + 8 * cs0;
  const u16* gV1 = Vh + (size_t)r1 * SEQ + 8 * cs1;
  int dst0 = 64 * r0 + 8 * c0, dst1 = 64 * r1 + 8 * c0;

  // hoisted fragment addresses (u16 indices into 64x64 swizzled tile)
  int koff0 = 64 * i + 8 * (g ^ (i & 7));
  int koff1 = 64 * i + 8 * ((g + 4) ^ (i & 7));
  int kvx = (i >> 1) & 3;
  int vbit = ((g >> 1) ^ (i & 1));
  int voff[4];
#pragma unroll
  for (int kvf = 0; kvf < 4; ++kvf)
    voff[kvf] = 64 * i + 8 * ((2 * (kvf ^ kvx)) | vbit) + 4 * (g & 1);

  {  // prologue: stage tile 0
    short8 a = *(const short8*)gK0, b2 = *(const short8*)gK1;
    short8 c = *(const short8*)gV0, d = *(const short8*)gV1;
    *(short8*)&lK[0][dst0] = a; *(short8*)&lK[0][dst1] = b2;
    *(short8*)&lV[0][dst0] = c; *(short8*)&lV[0][dst1] = d;
  }
  __syncthreads();

  const int NT = 64 - B;
  int cur = 0;
  short8 ka, kb2, va, vb;
  for (int t = 0; t < NT; ++t) {
    bool more = (t + 1 < NT);
    if (more) {  // issue next tile's global loads early
      ka = *(const short8*)(gK0 + (t + 1) * 64 * HD);
      kb2 = *(const short8*)(gK1 + (t + 1) * 64 * HD);
      va = *(const short8*)(gV0 + (t + 1) * 64);
      vb = *(const short8*)(gV1 + (t + 1) * 64);
    }
    const u16* lKb = lK[cur];
    const u16* lVb = lV[cur];
    bool doLo = (t <= B);
    f32x4 sh4[4] = {}, sl4[4] = {};
    __builtin_amdgcn_s_setprio(1);
#pragma unroll
    for (int kvf = 0; kvf < 4; ++kvf) {
      bf16x8 kf0 = ld8(&lKb[koff0 + 1024 * kvf]);
      bf16x8 kf1 = ld8(&lKb[koff1 + 1024 * kvf]);
      sh4[kvf] = MFMA32(kf0, qhi0, sh4[kvf]);
      sh4[kvf] = MFMA32(kf1, qhi1, sh4[kvf]);
      if (doLo) {
        sl4[kvf] = MFMA32(kf0, qlo0, sl4[kvf]);
        sl4[kvf] = MFMA32(kf1, qlo1, sl4[kvf]);
      }
    }
    __builtin_amdgcn_s_setprio(0);
    short4v pbh[4], pbl[4];
    if (doLo) {
      process2(sh4, m_hi, s_hi, o_hi, pbh, t == NT - 1, q_hi,
               sl4, m_lo, s_lo, o_lo, pbl, t == B, q_lo, t, g);
      __builtin_amdgcn_s_setprio(1);
#pragma unroll
      for (int df = 0; df < 4; ++df)
#pragma unroll
        for (int kvf = 0; kvf < 4; ++kvf) {
          short4v vf = *reinterpret_cast<const short4v*>(&lVb[voff[kvf] + 1024 * df]);
          o_hi[df] = mfma16(vf, pbh[kvf], o_hi[df]);
          o_lo[df] = mfma16(vf, pbl[kvf], o_lo[df]);
        }
      __builtin_amdgcn_s_setprio(0);
    } else {
      process1(sh4, m_hi, s_hi, o_hi, pbh, t == NT - 1, q_hi, t, g);
      __builtin_amdgcn_s_setprio(1);
#pragma unroll
      for (int df = 0; df < 4; ++df)
#pragma unroll
        for (int kvf = 0; kvf < 4; ++kvf) {
          short4v vf = *reinterpret_cast<const short4v*>(&lVb[voff[kvf] + 1024 * df]);
          o_hi[df] = mfma16(vf, pbh[kvf], o_hi[df]);
        }
      __builtin_amdgcn_s_setprio(0);
    }
    if (more) {
      u16* nK = lK[cur ^ 1];
      u16* nV = lV[cur ^ 1];
      *(short8*)&nK[dst0] = ka; *(short8*)&nK[dst1] = kb2;
      *(short8*)&nV[dst0] = va; *(short8*)&nV[dst1] = vb;
      __syncthreads();
    }
    cur ^= 1;
  }
  int b = bh / NHEAD, h = bh % NHEAD;
  store16(O, o_hi, s_hi, b, h, q_hi, g);
  store16(O, o_lo, s_lo, b, h, q_lo, g);
}

extern "C" void kernel_launch(void* const* d_in, const int* in_sizes, int n_in,
                              void* d_out, int out_size, void* d_ws, size_t ws_size,
                              hipStream_t stream) {
  const float* x = (const float*)d_in[0];
  const float* W_attn = (const float*)d_in[1];
  const float* b_attn = (const float*)d_in[2];
  const float* W_out = (const float*)d_in[3];
  const float* b_out = (const float*)d_in[4];
  float* out = (float*)d_out;

  char* ws = (char*)d_ws;
  u16* xb = (u16*)(ws + 0);              // 8192*768*2       = 12,582,912
  u16* waT = (u16*)(ws + 12582912);      // 2304*768*2       =  3,538,944
  u16* woT = (u16*)(ws + 16121856);      // 768*768*2        =  1,179,648
  u16* q = (u16*)(ws + 17301504);        // 12,582,912
  u16* kk = (u16*)(ws + 29884416);       // 12,582,912
  u16* v = (u16*)(ws + 42467328);        // 12,582,912  (transposed [b][h][d][n])
  u16* ao = (u16*)(ws + 67633152);       // 12,582,912  (end 80,216,064)

  k_convert<<<1536, 256, 0, stream>>>(x, xb, M_TOK * C_EMBD / 4);
  k_tconv<<<dim3(N_QKV / 32, C_EMBD / 32), 256, 0, stream>>>(W_attn, waT, C_EMBD, N_QKV);
  k_tconv<<<dim3(C_EMBD / 32, C_EMBD / 32), 256, 0, stream>>>(W_out, woT, C_EMBD, C_EMBD);
  k_gemm<0><<<dim3(M_TOK / 128, N_QKV / 128), 256, 0, stream>>>(
      xb, waT, b_attn, q, kk, v, nullptr, C_EMBD);
  k_attn<<<768, 256, 0, stream>>>(q, kk, v, ao);
  k_gemm<1><<<dim3(M_TOK / 128, C_EMBD / 128), 256, 0, stream>>>(
      ao, woT, b_out, nullptr, nullptr, nullptr, out, C_EMBD);
}

// Round 6
// 213.402 us; speedup vs baseline: 2.0179x; 1.5859x over previous
//
#include <hip/hip_runtime.h>
#include <hip/hip_bf16.h>
#include <stdint.h>

typedef unsigned short u16;
typedef __bf16 bf16_t;
typedef bf16_t bf16x8 __attribute__((ext_vector_type(8)));
typedef float f32x4 __attribute__((ext_vector_type(4)));
typedef short short8 __attribute__((ext_vector_type(8)));
typedef short short4v __attribute__((ext_vector_type(4)));
typedef u16 u16x4 __attribute__((ext_vector_type(4)));

#define C_EMBD 768
#define NHEAD 12
#define HD 64
#define SEQ 4096
#define BATCH 2
#define M_TOK (BATCH * SEQ)   // 8192
#define N_QKV (3 * C_EMBD)    // 2304

__device__ __forceinline__ u16 f2bf(float f) {
  return __builtin_bit_cast(u16, (bf16_t)f);
}
__device__ __forceinline__ bf16x8 ld8(const u16* p) {
  return __builtin_bit_cast(bf16x8, *reinterpret_cast<const short8*>(p));
}
__device__ __forceinline__ void async16(const u16* g, u16* l) {
  __builtin_amdgcn_global_load_lds(
      (__attribute__((address_space(1))) void*)g,
      (__attribute__((address_space(3))) void*)l, 16, 0, 0);
}

#define MFMA32(a, b, c) __builtin_amdgcn_mfma_f32_16x16x32_bf16(a, b, c, 0, 0, 0)

__device__ __forceinline__ f32x4 mfma16(short4v a, short4v b, f32x4 c) {
#if __has_builtin(__builtin_amdgcn_mfma_f32_16x16x16bf16_1k)
  return __builtin_amdgcn_mfma_f32_16x16x16bf16_1k(a, b, c, 0, 0, 0);
#else
  asm volatile("v_mfma_f32_16x16x16_bf16 %0, %1, %2, %0"
               : "+v"(c) : "v"(a), "v"(b));
  return c;
#endif
}

// ---------------- fp32 -> bf16 convert (x) ----------------
__global__ __launch_bounds__(256) void k_convert(const float* __restrict__ in,
                                                 u16* __restrict__ out, int n4) {
  int i = blockIdx.x * blockDim.x + threadIdx.x;
  int stride = gridDim.x * blockDim.x;
  for (; i < n4; i += stride) {
    float4 v = reinterpret_cast<const float4*>(in)[i];
    u16x4 o;
    o.x = f2bf(v.x); o.y = f2bf(v.y); o.z = f2bf(v.z); o.w = f2bf(v.w);
    reinterpret_cast<u16x4*>(out)[i] = o;
  }
}

// ------------- transpose + convert weights: W[R][C] -> WT[C][R] bf16 -------------
__global__ __launch_bounds__(256) void k_tconv(const float* __restrict__ W,
                                               u16* __restrict__ WT, int R, int C) {
  __shared__ float t[32][33];
  int c0 = blockIdx.x * 32, r0 = blockIdx.y * 32;
  int tid = threadIdx.x;
  int a = tid >> 3, b = (tid & 7) * 4;
  float4 v = *reinterpret_cast<const float4*>(W + (size_t)(r0 + a) * C + c0 + b);
  t[a][b] = v.x; t[a][b + 1] = v.y; t[a][b + 2] = v.z; t[a][b + 3] = v.w;
  __syncthreads();
  u16x4 o;
  o.x = f2bf(t[b + 0][a]); o.y = f2bf(t[b + 1][a]);
  o.z = f2bf(t[b + 2][a]); o.w = f2bf(t[b + 3][a]);
  *reinterpret_cast<u16x4*>(WT + (size_t)(c0 + a) * R + r0 + b) = o;
}

// ------------- GEMM: C[M,N] = A[M,K] * Bt[N,K]^T + bias -------------
template <int MODE>
__global__ __launch_bounds__(256) void k_gemm(const u16* __restrict__ A,
                                              const u16* __restrict__ Bt,
                                              const float* __restrict__ bias,
                                              u16* __restrict__ q_out,
                                              u16* __restrict__ k_out,
                                              u16* __restrict__ v_out,
                                              float* __restrict__ fout, int K) {
  __shared__ __align__(16) u16 lA[128 * 32];
  __shared__ __align__(16) u16 lB[128 * 32];
  int tid = threadIdx.x;
  int bm = blockIdx.x, bn = blockIdx.y;
  int w = tid >> 6, l = tid & 63;
  int wr = w >> 1, wc = w & 1;
  int lrow = l & 15, lk = (l >> 4) * 8;
  f32x4 acc[4][4] = {};

  int srow = tid >> 2, scol = (tid & 3) * 8;
  const u16* gA0 = A + (size_t)(bm * 128 + srow) * K + scol;
  const u16* gA1 = A + (size_t)(bm * 128 + 64 + srow) * K + scol;
  const u16* gB0 = Bt + (size_t)(bn * 128 + srow) * K + scol;
  const u16* gB1 = Bt + (size_t)(bn * 128 + 64 + srow) * K + scol;
  u16* lA0 = lA + w * 512;
  u16* lA1 = lA + 2048 + w * 512;
  u16* lB0 = lB + w * 512;
  u16* lB1 = lB + 2048 + w * 512;

  for (int k0 = 0; k0 < K; k0 += 32) {
    __syncthreads();
    async16(gA0 + k0, lA0);
    async16(gA1 + k0, lA1);
    async16(gB0 + k0, lB0);
    async16(gB1 + k0, lB1);
    __syncthreads();
    bf16x8 af[4], bfr[4];
#pragma unroll
    for (int mf = 0; mf < 4; ++mf)
      af[mf] = ld8(&lA[(wr * 64 + mf * 16 + lrow) * 32 + lk]);
#pragma unroll
    for (int nf = 0; nf < 4; ++nf)
      bfr[nf] = ld8(&lB[(wc * 64 + nf * 16 + lrow) * 32 + lk]);
#pragma unroll
    for (int mf = 0; mf < 4; ++mf)
#pragma unroll
      for (int nf = 0; nf < 4; ++nf)
        acc[mf][nf] = __builtin_amdgcn_mfma_f32_16x16x32_bf16(
            af[mf], bfr[nf], acc[mf][nf], 0, 0, 0);
  }

#pragma unroll
  for (int nf = 0; nf < 4; ++nf) {
    int col = bn * 128 + wc * 64 + nf * 16 + lrow;
    float bv = bias[col];
#pragma unroll
    for (int mf = 0; mf < 4; ++mf) {
      int row0 = bm * 128 + wr * 64 + mf * 16 + (l >> 4) * 4;
#pragma unroll
      for (int r = 0; r < 4; ++r) {
        float val = acc[mf][nf][r] + bv;
        int row = row0 + r;
        if constexpr (MODE == 0) {
          int which = (col >= 2 * C_EMBD) ? 2 : ((col >= C_EMBD) ? 1 : 0);
          int wi = col - which * C_EMBD;
          int head = wi >> 6, dd = wi & 63;
          int b = row >> 12, n = row & 4095;
          if (which == 2) {
            v_out[(((size_t)b * NHEAD + head) * HD + dd) * SEQ + n] = f2bf(val);
          } else {
            u16* dst = (which == 0) ? q_out : k_out;
            dst[(((size_t)b * NHEAD + head) * SEQ + n) * HD + dd] = f2bf(val);
          }
        } else {
          fout[(size_t)row * C_EMBD + col] = val;
        }
      }
    }
  }
}

// ------------- attention helpers -------------
#define CE_CONST (0.125f * 1.44269504088896f)  // scale * log2(e)

__device__ __forceinline__ void mask_diag(f32x4 (&s4)[4], int qrow, int t, int g) {
  int kb = 64 * t + 4 * g;
#pragma unroll
  for (int kvf = 0; kvf < 4; ++kvf)
#pragma unroll
    for (int r = 0; r < 4; ++r)
      if (kb + 16 * kvf + r > qrow) s4[kvf][r] = -1e30f;
}

__device__ __forceinline__ void process1(f32x4 (&s4)[4], float& mst, float& lsum,
                                         f32x4 (&o)[4], short4v (&pb)[4],
                                         bool diag, int qrow, int t, int g) {
  if (diag) mask_diag(s4, qrow, t, g);
  f32x4 mx = s4[0];
#pragma unroll
  for (int kvf = 1; kvf < 4; ++kvf)
#pragma unroll
    for (int r = 0; r < 4; ++r) mx[r] = fmaxf(mx[r], s4[kvf][r]);
  float rmax = fmaxf(fmaxf(mx[0], mx[1]), fmaxf(mx[2], mx[3]));
  rmax = fmaxf(rmax, __shfl_xor(rmax, 16));
  rmax = fmaxf(rmax, __shfl_xor(rmax, 32));
  bool keep = __all(rmax <= mst + 44.0f);  // defer-max: P bounded by ~2^8
  float mnew = keep ? mst : fmaxf(mst, rmax);
  float mCE = mnew * CE_CONST;
  float rs = 0.f;
#pragma unroll
  for (int kvf = 0; kvf < 4; ++kvf) {
    f32x4 pf;
#pragma unroll
    for (int r = 0; r < 4; ++r) {
      pf[r] = exp2f(s4[kvf][r] * CE_CONST - mCE);
      pb[kvf][r] = (short)f2bf(pf[r]);
    }
    rs += (pf[0] + pf[1]) + (pf[2] + pf[3]);
  }
  rs += __shfl_xor(rs, 16);
  rs += __shfl_xor(rs, 32);
  if (keep) {
    lsum += rs;
  } else {
    float sc = exp2f((mst - mnew) * CE_CONST);
    lsum = lsum * sc + rs;
#pragma unroll
    for (int df = 0; df < 4; ++df) o[df] *= sc;
    mst = mnew;
  }
}

__device__ __forceinline__ void store16(u16* __restrict__ O, const f32x4 (&o)[4],
                                        float ssum, int b, int h, int q, int g) {
  float inv = 1.0f / ssum;
  size_t base = ((size_t)b * SEQ + q) * C_EMBD + h * HD;
#pragma unroll
  for (int df = 0; df < 4; ++df) {
    u16x4 pk;
#pragma unroll
    for (int r = 0; r < 4; ++r) pk[r] = f2bf(o[df][r] * inv);
    *reinterpret_cast<u16x4*>(&O[base + df * 16 + 4 * g]) = pk;
  }
}

// ------------- causal flash attention, single-stream, LPT-scheduled -------------
// 1536 blocks = 24 bh x 64 q-tiles, ordered longest-first (qt=63 dispatched
// first) for LPT packing. 4 waves x 16 q-rows. 5 blocks/CU (LDS 32KB, VGPR<=102)
// -> 20 waves/CU; independent blocks hide each other's barrier/softmax stalls.
__global__ __launch_bounds__(256, 5) void k_attn(const u16* __restrict__ Q,
                                                 const u16* __restrict__ Kb,
                                                 const u16* __restrict__ VTb,
                                                 u16* __restrict__ O) {
  int blk = blockIdx.x;
  int qt = 63 - (blk / 24);        // LPT: big tiles first
  int bh = blk % 24;               // consecutive blocks -> different bh/XCD
  const u16* Qh = Q + (size_t)bh * SEQ * HD;
  const u16* Kh = Kb + (size_t)bh * SEQ * HD;
  const u16* Vh = VTb + (size_t)bh * HD * SEQ;  // [64][4096]
  int tid = threadIdx.x, w = tid >> 6, l = tid & 63;
  int i = l & 15, g = l >> 4;

  __shared__ __align__(16) u16 lK[2][64 * 64];
  __shared__ __align__(16) u16 lV[2][64 * 64];

  int qr = qt * 64 + w * 16 + i;
  bf16x8 qf0 = ld8(Qh + (size_t)qr * HD + g * 8);
  bf16x8 qf1 = ld8(Qh + (size_t)qr * HD + 32 + g * 8);
  f32x4 o[4] = {};
  float mst = -1e30f, lsum = 0.f;

  // staging: 256 threads x (2 K-chunks + 2 V-chunks) of 16B
  int r0 = tid >> 3, c0 = tid & 7;
  int cs0 = c0 ^ (r0 & 7);
  int r1 = r0 + 32, cs1 = c0 ^ (r1 & 7);
  const u16* gK0 = Kh + r0 * HD + 8 * cs0;
  const u16* gK1 = Kh + r1 * HD + 8 * cs1;
  const u16* gV0 = Vh + (size_t)r0 * SEQ + 8 * cs0;
  const u16* gV1 = Vh + (size_t)r1 * SEQ + 8 * cs1;
  int dst0 = 64 * r0 + 8 * c0, dst1 = 64 * r1 + 8 * c0;

  // hoisted fragment addresses (u16 indices into 64x64 swizzled tile)
  int koff0 = 64 * i + 8 * (g ^ (i & 7));
  int koff1 = 64 * i + 8 * ((g + 4) ^ (i & 7));
  int kvx = (i >> 1) & 3;
  int vbit = ((g >> 1) ^ (i & 1));
  int voff[4];
#pragma unroll
  for (int kvf = 0; kvf < 4; ++kvf)
    voff[kvf] = 64 * i + 8 * ((2 * (kvf ^ kvx)) | vbit) + 4 * (g & 1);

  {  // prologue: stage tile 0
    short8 a = *(const short8*)gK0, b2 = *(const short8*)gK1;
    short8 c = *(const short8*)gV0, d = *(const short8*)gV1;
    *(short8*)&lK[0][dst0] = a; *(short8*)&lK[0][dst1] = b2;
    *(short8*)&lV[0][dst0] = c; *(short8*)&lV[0][dst1] = d;
  }
  __syncthreads();

  const int NT = qt + 1;
  int cur = 0;
  short8 ka, kb2, va, vb;
  for (int t = 0; t < NT; ++t) {
    bool more = (t + 1 < NT);
    if (more) {  // issue next tile's global loads early
      ka = *(const short8*)(gK0 + (t + 1) * 64 * HD);
      kb2 = *(const short8*)(gK1 + (t + 1) * 64 * HD);
      va = *(const short8*)(gV0 + (t + 1) * 64);
      vb = *(const short8*)(gV1 + (t + 1) * 64);
    }
    const u16* lKb = lK[cur];
    const u16* lVb = lV[cur];
    f32x4 s4[4] = {};
    __builtin_amdgcn_s_setprio(1);
#pragma unroll
    for (int kvf = 0; kvf < 4; ++kvf) {
      bf16x8 kf0 = ld8(&lKb[koff0 + 1024 * kvf]);
      bf16x8 kf1 = ld8(&lKb[koff1 + 1024 * kvf]);
      s4[kvf] = MFMA32(kf0, qf0, s4[kvf]);
      s4[kvf] = MFMA32(kf1, qf1, s4[kvf]);
    }
    __builtin_amdgcn_s_setprio(0);
    short4v pb[4];
    process1(s4, mst, lsum, o, pb, t == NT - 1, qr, t, g);
    __builtin_amdgcn_s_setprio(1);
#pragma unroll
    for (int df = 0; df < 4; ++df)
#pragma unroll
      for (int kvf = 0; kvf < 4; ++kvf) {
        short4v vf = *reinterpret_cast<const short4v*>(&lVb[voff[kvf] + 1024 * df]);
        o[df] = mfma16(vf, pb[kvf], o[df]);
      }
    __builtin_amdgcn_s_setprio(0);
    if (more) {
      u16* nK = lK[cur ^ 1];
      u16* nV = lV[cur ^ 1];
      *(short8*)&nK[dst0] = ka; *(short8*)&nK[dst1] = kb2;
      *(short8*)&nV[dst0] = va; *(short8*)&nV[dst1] = vb;
      __syncthreads();
    }
    cur ^= 1;
  }
  int b = bh / NHEAD, h = bh % NHEAD;
  store16(O, o, lsum, b, h, qr, g);
}

extern "C" void kernel_launch(void* const* d_in, const int* in_sizes, int n_in,
                              void* d_out, int out_size, void* d_ws, size_t ws_size,
                              hipStream_t stream) {
  const float* x = (const float*)d_in[0];
  const float* W_attn = (const float*)d_in[1];
  const float* b_attn = (const float*)d_in[2];
  const float* W_out = (const float*)d_in[3];
  const float* b_out = (const float*)d_in[4];
  float* out = (float*)d_out;

  char* ws = (char*)d_ws;
  u16* xb = (u16*)(ws + 0);              // 8192*768*2       = 12,582,912
  u16* waT = (u16*)(ws + 12582912);      // 2304*768*2       =  3,538,944
  u16* woT = (u16*)(ws + 16121856);      // 768*768*2        =  1,179,648
  u16* q = (u16*)(ws + 17301504);        // 12,582,912
  u16* kk = (u16*)(ws + 29884416);       // 12,582,912
  u16* v = (u16*)(ws + 42467328);        // 12,582,912  (transposed [b][h][d][n])
  u16* ao = (u16*)(ws + 67633152);       // 12,582,912  (end 80,216,064)

  k_convert<<<1536, 256, 0, stream>>>(x, xb, M_TOK * C_EMBD / 4);
  k_tconv<<<dim3(N_QKV / 32, C_EMBD / 32), 256, 0, stream>>>(W_attn, waT, C_EMBD, N_QKV);
  k_tconv<<<dim3(C_EMBD / 32, C_EMBD / 32), 256, 0, stream>>>(W_out, woT, C_EMBD, C_EMBD);
  k_gemm<0><<<dim3(M_TOK / 128, N_QKV / 128), 256, 0, stream>>>(
      xb, waT, b_attn, q, kk, v, nullptr, C_EMBD);
  k_attn<<<1536, 256, 0, stream>>>(q, kk, v, ao);
  k_gemm<1><<<dim3(M_TOK / 128, C_EMBD / 128), 256, 0, stream>>>(
      ao, woT, b_out, nullptr, nullptr, nullptr, out, C_EMBD);
}